// Round 10
// baseline (50.198 us; speedup 1.0000x reference)
//
#include <hip/hip_runtime.h>
#include <hip/hip_bf16.h>

#define B_ 4
#define N_ 20000
#define D_ 128
#define E_ 100000
#define NT_ 1250     // 16-node tiles (20000/16 exact)

typedef __attribute__((ext_vector_type(8))) short bf16x8;
typedef __attribute__((ext_vector_type(4))) float f32x4;

// ws layout (float units):
// [0]              flag (int)
// [128,640)        g (B_ x D_)   -- zeroed by hipMemsetAsync each call
// [640,896)        w5f (float2[128]: {w5_i[c], w5_j[c]})
// [1024,9216)      w7f: 2048 x bf16x8 (32 KB), MFMA B-fragment order
// [9216,89216)     qi (B x N)
// [89216,169216)   qj (B x N)

// bx 0..7: W7 -> fragments; bx 8: flag + w5f; bx 9..520: g-sum (streaming)
__global__ __launch_bounds__(256) void k_prep(
    const float* __restrict__ W7, const float* __restrict__ w5,
    const float* __restrict__ emb, const unsigned* __restrict__ ew,
    int* __restrict__ flag, float* __restrict__ g,
    float2* __restrict__ w5f, bf16x8* __restrict__ w7f)
{
    __shared__ float4 sred[8][32];
    const int bx = blockIdx.x, t = threadIdx.x;
    if (bx < 8) {
        int f = bx * 256 + t;                    // 0..2047
        int tt = f >> 8, s = (f >> 6) & 3, lane = f & 63;
        int kg = lane >> 4, rc = lane & 15;
        int col = tt * 16 + rc, k0 = s * 32 + kg * 8;
        union { bf16x8 v; __hip_bfloat16 h[8]; } pk;
        #pragma unroll
        for (int m = 0; m < 8; ++m)
            pk.h[m] = __float2bfloat16(W7[(k0 + m) * D_ + col]);
        w7f[f] = pk.v;
        return;
    }
    if (bx == 8) {
        if (t < 128) w5f[t] = make_float2(w5[D_ + t], w5[2 * D_ + t]);
        if (t < 64) {
            unsigned v = ew[2 * t + 1];      // high words if int64 (all zero)
            unsigned long long any = __ballot(v != 0u);
            if (t == 0) *flag = (any == 0ULL) ? 1 : 0;
        }
        return;
    }
    // ---- g-sum: 512 blocks, batch b = chunk>>7, rows chunk*157..+157
    const int gb = bx - 9;
    const int b = gb >> 7, chunk = gb & 127;
    const int r0 = chunk * 157;
    const int c4 = t & 31, rg = t >> 5;
    const float4* eb = (const float4*)(emb + (size_t)b * N_ * D_);
    float4 s = make_float4(0.f, 0.f, 0.f, 0.f);
    #pragma unroll
    for (int i = 0; i < 20; ++i) {
        int rr = rg + 8 * i;
        int r = r0 + rr;
        if (rr < 157 && r < N_) {
            float4 v = eb[r * 32 + c4];
            s.x += v.x; s.y += v.y; s.z += v.z; s.w += v.w;
        }
    }
    sred[rg][c4] = s;
    __syncthreads();
    if (t < 32) {
        float4 acc = sred[0][t];
        #pragma unroll
        for (int v2 = 1; v2 < 8; ++v2) {
            float4 q = sred[v2][t];
            acc.x += q.x; acc.y += q.y; acc.z += q.z; acc.w += q.w;
        }
        float* gp = g + b * D_ + t * 4;
        atomicAdd(gp + 0, acc.x);
        atomicAdd(gp + 1, acc.y);
        atomicAdd(gp + 2, acc.z);
        atomicAdd(gp + 3, acc.w);
    }
}

// R5 structure minus all g work: A direct-from-global fragments, LDS B table.
__global__ __launch_bounds__(256) void k_main(
    const float* __restrict__ emb, const bf16x8* __restrict__ w7f,
    const float2* __restrict__ w5f,
    float* __restrict__ qi, float* __restrict__ qj)
{
    __shared__ bf16x8 sB[2048];   // fragment order: idx = tt*256 + s*64 + lane

    const int t = threadIdx.x, b = blockIdx.y;
    const int wv = t >> 6, lane = t & 63, rc = lane & 15, kg = lane >> 4;
    const int tile = blockIdx.x * 4 + wv;
    const int tc = (tile < NT_) ? tile : (NT_ - 1);

    // ---- A loads first (8 independent dwordx4)
    const float4* p = (const float4*)(emb + (size_t)b * N_ * D_)
                      + ((size_t)(tc * 16 + rc)) * 32 + kg * 2;
    float4 a[8];
    #pragma unroll
    for (int s = 0; s < 4; ++s) { a[2*s] = p[s*8]; a[2*s+1] = p[s*8+1]; }

    // ---- stage B (coalesced uint4, L2-resident source)
    {
        const uint4* src = (const uint4*)w7f;
        uint4* dst = (uint4*)sB;
        #pragma unroll
        for (int i = 0; i < 8; ++i) dst[t + 256 * i] = src[t + 256 * i];
    }
    float2 wij[8];
    #pragma unroll
    for (int tt = 0; tt < 8; ++tt) wij[tt] = w5f[tt * 16 + rc];
    __syncthreads();

    // ---- cvt A to bf16 fragments
    bf16x8 pk[4];
    #pragma unroll
    for (int s = 0; s < 4; ++s) {
        union { bf16x8 v; __hip_bfloat16 h[8]; } u;
        float4 x = a[2*s], y = a[2*s+1];
        u.h[0] = __float2bfloat16(x.x); u.h[1] = __float2bfloat16(x.y);
        u.h[2] = __float2bfloat16(x.z); u.h[3] = __float2bfloat16(x.w);
        u.h[4] = __float2bfloat16(y.x); u.h[5] = __float2bfloat16(y.y);
        u.h[6] = __float2bfloat16(y.z); u.h[7] = __float2bfloat16(y.w);
        pk[s] = u.v;
    }

    // ---- MFMA: 16 nodes x 128 cols, K=128
    f32x4 acc[8] = {};
    #pragma unroll
    for (int s = 0; s < 4; ++s)
        #pragma unroll
        for (int tt = 0; tt < 8; ++tt)
            acc[tt] = __builtin_amdgcn_mfma_f32_16x16x32_bf16(pk[s], sB[tt * 256 + s * 64 + lane], acc[tt], 0, 0, 0);

    // ---- epilogue: leaky, dot w5_i/w5_j, shfl-reduce over rc, store
    float qip[4] = {0,0,0,0}, qjp[4] = {0,0,0,0};
    #pragma unroll
    for (int tt = 0; tt < 8; ++tt) {
        #pragma unroll
        for (int r = 0; r < 4; ++r) {
            float pv = acc[tt][r];
            float lr = (pv >= 0.f) ? pv : 0.01f * pv;
            qip[r] += lr * wij[tt].x;
            qjp[r] += lr * wij[tt].y;
        }
    }
    #pragma unroll
    for (int m = 1; m < 16; m <<= 1) {
        #pragma unroll
        for (int r = 0; r < 4; ++r) {
            qip[r] += __shfl_xor(qip[r], m);
            qjp[r] += __shfl_xor(qjp[r], m);
        }
    }
    if (tile < NT_ && rc == 0) {
        #pragma unroll
        for (int r = 0; r < 4; ++r) {
            int node = tile * 16 + kg * 4 + r;
            qi[b * N_ + node] = qip[r];
            qj[b * N_ + node] = qjp[r];
        }
    }
}

// fused tail: per-block redundant qg from g (cheap, L2-hot) + edge gather
__global__ __launch_bounds__(256) void k_tail(
    const int* __restrict__ edges, const int* __restrict__ flag,
    const float* __restrict__ g, const float* __restrict__ W6,
    const float* __restrict__ w5, const float* __restrict__ wno,
    const float* __restrict__ qi, const float* __restrict__ qj,
    float* __restrict__ out)
{
    __shared__ float sg[B_][D_];
    __shared__ float4 srw[4];
    __shared__ float sqg[B_];

    const int t = threadIdx.x;
    const int col = t & 127, h = t >> 7, wave = t >> 6, lane = t & 63;

    if (t < 128) {
        #pragma unroll
        for (int b = 0; b < B_; ++b) sg[b][t] = g[b * D_ + t];
    }
    __syncthreads();

    // thread handles batches h and h+2 at column col
    float p0 = 0.f, p1 = 0.f;
    #pragma unroll 8
    for (int d = 0; d < 128; ++d) {
        float w6 = W6[d * D_ + col];
        p0 += sg[h][d] * w6;
        p1 += sg[h + 2][d] * w6;
    }
    float l0 = (p0 >= 0.f) ? p0 : 0.01f * p0;
    float l1 = (p1 >= 0.f) ? p1 : 0.01f * p1;
    float w5g = w5[col], wn = wno[col];
    float vq0 = l0 * w5g, vq1 = l1 * w5g;
    float vn0 = sg[h][col] * wn, vn1 = sg[h + 2][col] * wn;
    #pragma unroll
    for (int m = 1; m < 64; m <<= 1) {
        vq0 += __shfl_xor(vq0, m);
        vq1 += __shfl_xor(vq1, m);
        vn0 += __shfl_xor(vn0, m);
        vn1 += __shfl_xor(vn1, m);
    }
    if (lane == 0) srw[wave] = make_float4(vq0, vq1, vn0, vn1);
    __syncthreads();
    if (t == 0) {
        float4 a0 = srw[0], a1 = srw[1], a2 = srw[2], a3 = srw[3];
        sqg[0] = a0.x + a1.x;   // b0: waves 0,1 (h=0) vq0
        sqg[2] = a0.y + a1.y;   // b2: vq1
        sqg[1] = a2.x + a3.x;   // b1: waves 2,3 (h=1) vq0
        sqg[3] = a2.y + a3.y;   // b3: vq1
        if (blockIdx.x == 0) {
            out[0 * (size_t)(E_ + 1) + E_] = a0.z + a1.z;
            out[2 * (size_t)(E_ + 1) + E_] = a0.w + a1.w;
            out[1 * (size_t)(E_ + 1) + E_] = a2.z + a3.z;
            out[3 * (size_t)(E_ + 1) + E_] = a2.w + a3.w;
        }
    }
    __syncthreads();

    const int e = blockIdx.x * 256 + t;
    if (e < E_) {
        int u, v;
        if (*flag) { int4 w = ((const int4*)edges)[e]; u = w.x; v = w.z; }
        else       { int2 w = ((const int2*)edges)[e]; u = w.x; v = w.y; }
        float q0 = sqg[0], q1 = sqg[1], q2 = sqg[2], q3 = sqg[3];
        out[0 * (size_t)(E_ + 1) + e] = q0 + qi[0 * N_ + u] + qj[0 * N_ + v];
        out[1 * (size_t)(E_ + 1) + e] = q1 + qi[1 * N_ + u] + qj[1 * N_ + v];
        out[2 * (size_t)(E_ + 1) + e] = q2 + qi[2 * N_ + u] + qj[2 * N_ + v];
        out[3 * (size_t)(E_ + 1) + e] = q3 + qi[3 * N_ + u] + qj[3 * N_ + v];
    }
}

extern "C" void kernel_launch(void* const* d_in, const int* in_sizes, int n_in,
                              void* d_out, int out_size, void* d_ws, size_t ws_size,
                              hipStream_t stream)
{
    const float* emb   = (const float*)d_in[0];
    const int*   edges = (const int*)d_in[1];
    const float* W6    = (const float*)d_in[2];
    const float* W7    = (const float*)d_in[3];
    const float* w5    = (const float*)d_in[4];
    const float* wno   = (const float*)d_in[5];
    float* out = (float*)d_out;

    float* W = (float*)d_ws;
    int*     flag = (int*)W;
    float*   g    = W + 128;
    float2*  w5f  = (float2*)(W + 640);
    bf16x8*  w7f  = (bf16x8*)(W + 1024);
    float*   qi   = W + 9216;
    float*   qj   = W + 89216;

    hipMemsetAsync(g, 0, B_ * D_ * sizeof(float), stream);
    hipLaunchKernelGGL(k_prep, dim3(521), dim3(256), 0, stream,
                       W7, w5, emb, (const unsigned*)edges, flag, g, w5f, w7f);
    hipLaunchKernelGGL(k_main, dim3(313, B_), dim3(256), 0, stream,
                       emb, w7f, w5f, qi, qj);
    hipLaunchKernelGGL(k_tail, dim3((E_ + 255) / 256), dim3(256), 0, stream,
                       edges, flag, g, W6, w5, wno, qi, qj, out);
}

// Round 11
// 48.214 us; speedup vs baseline: 1.0412x; 1.0412x over previous
//
#include <hip/hip_runtime.h>
#include <hip/hip_bf16.h>

#define B_ 4
#define N_ 20000
#define D_ 128
#define E_ 100000
#define NT_ 1250     // 16-node tiles (20000/16 exact)
#define GRB_ 50      // greduce blocks

typedef __attribute__((ext_vector_type(8))) short bf16x8;
typedef __attribute__((ext_vector_type(4))) float f32x4;

// ws layout (float units):
// [0]              flag (int)
// [4]              cnt (unsigned)
// [8,12)           qg (B_)
// [128,640)        g (B_ x D_)
// [640,896)        w5f (float2[128]: {w5_i[c], w5_j[c]})
// [1024,9216)      w7f: 2048 x bf16x8 (32 KB), MFMA B-fragment order
// [9216,649216)    gpart[1250][512]
// [649216,729216)  qi (B x N)
// [729216,809216)  qj (B x N)

__global__ __launch_bounds__(256) void k_prep(
    const float* __restrict__ W7, const float* __restrict__ w5,
    const unsigned* __restrict__ ew, int* __restrict__ flag,
    unsigned* __restrict__ cnt, float* __restrict__ g,
    float2* __restrict__ w5f, bf16x8* __restrict__ w7f)
{
    const int bx = blockIdx.x, t = threadIdx.x;
    if (bx == 8) {
        g[t] = 0.f; g[t + 256] = 0.f;
        if (t < 128) w5f[t] = make_float2(w5[D_ + t], w5[2 * D_ + t]);
        if (t == 0) *cnt = 0u;
        if (t < 64) {
            unsigned v = ew[2 * t + 1];      // high words if int64 (all zero)
            unsigned long long any = __ballot(v != 0u);
            if (t == 0) *flag = (any == 0ULL) ? 1 : 0;
        }
        return;
    }
    int f = bx * 256 + t;                    // 0..2047
    int tt = f >> 8, s = (f >> 6) & 3, lane = f & 63;
    int kg = lane >> 4, rc = lane & 15;
    int col = tt * 16 + rc, k0 = s * 32 + kg * 8;
    union { bf16x8 v; __hip_bfloat16 h[8]; } pk;
    #pragma unroll
    for (int m = 0; m < 8; ++m)
        pk.h[m] = __float2bfloat16(W7[(k0 + m) * D_ + col]);
    w7f[f] = pk.v;
}

// R5's best-measured k_main: A loads first, LDS B table, g scatter (no atomics).
__global__ __launch_bounds__(256) void k_main(
    const float* __restrict__ emb, const bf16x8* __restrict__ w7f,
    const float2* __restrict__ w5f, float* __restrict__ gpart,
    float* __restrict__ qi, float* __restrict__ qj)
{
    __shared__ bf16x8 sB[2048];   // fragment order: idx = tt*256 + s*64 + lane

    const int t = threadIdx.x, b = blockIdx.y;
    const int wv = t >> 6, lane = t & 63, rc = lane & 15, kg = lane >> 4;
    const int tile = blockIdx.x * 4 + wv;
    const int tc = (tile < NT_) ? tile : (NT_ - 1);

    // ---- issue A loads (HBM, deepest latency) first
    const float4* p = (const float4*)(emb + (size_t)b * N_ * D_)
                      + ((size_t)(tc * 16 + rc)) * 32 + kg * 2;
    float4 a[8];
    #pragma unroll
    for (int s = 0; s < 4; ++s) { a[2*s] = p[s*8]; a[2*s+1] = p[s*8+1]; }

    // ---- stage B (coalesced uint4, L2-resident source)
    {
        const uint4* src = (const uint4*)w7f;
        uint4* dst = (uint4*)sB;
        #pragma unroll
        for (int i = 0; i < 8; ++i) dst[t + 256 * i] = src[t + 256 * i];
    }
    float2 wij[8];
    #pragma unroll
    for (int tt = 0; tt < 8; ++tt) wij[tt] = w5f[tt * 16 + rc];
    __syncthreads();

    // ---- cvt A to bf16 fragments (a[] stays live for g)
    bf16x8 pk[4];
    #pragma unroll
    for (int s = 0; s < 4; ++s) {
        union { bf16x8 v; __hip_bfloat16 h[8]; } u;
        float4 x = a[2*s], y = a[2*s+1];
        u.h[0] = __float2bfloat16(x.x); u.h[1] = __float2bfloat16(x.y);
        u.h[2] = __float2bfloat16(x.z); u.h[3] = __float2bfloat16(x.w);
        u.h[4] = __float2bfloat16(y.x); u.h[5] = __float2bfloat16(y.y);
        u.h[6] = __float2bfloat16(y.z); u.h[7] = __float2bfloat16(y.w);
        pk[s] = u.v;
    }

    // ---- g partials (frees a[]; stores fly under MFMA)
    #pragma unroll
    for (int m = 1; m < 16; m <<= 1) {
        #pragma unroll
        for (int i = 0; i < 8; ++i) {
            a[i].x += __shfl_xor(a[i].x, m);
            a[i].y += __shfl_xor(a[i].y, m);
            a[i].z += __shfl_xor(a[i].z, m);
            a[i].w += __shfl_xor(a[i].w, m);
        }
    }
    if (tile < NT_ && rc == 0) {
        float* gp = gpart + (size_t)tile * 512 + b * 128;
        #pragma unroll
        for (int s = 0; s < 4; ++s) {
            int c0 = s * 32 + kg * 8;
            *reinterpret_cast<float4*>(gp + c0)     = a[2*s];
            *reinterpret_cast<float4*>(gp + c0 + 4) = a[2*s+1];
        }
    }

    // ---- MFMA: 16 nodes x 128 cols, K=128
    f32x4 acc[8] = {};
    #pragma unroll
    for (int s = 0; s < 4; ++s)
        #pragma unroll
        for (int tt = 0; tt < 8; ++tt)
            acc[tt] = __builtin_amdgcn_mfma_f32_16x16x32_bf16(pk[s], sB[tt * 256 + s * 64 + lane], acc[tt], 0, 0, 0);

    // ---- epilogue: leaky, dot w5_i/w5_j, shfl-reduce over rc, store
    float qip[4] = {0,0,0,0}, qjp[4] = {0,0,0,0};
    #pragma unroll
    for (int tt = 0; tt < 8; ++tt) {
        #pragma unroll
        for (int r = 0; r < 4; ++r) {
            float pv = acc[tt][r];
            float lr = (pv >= 0.f) ? pv : 0.01f * pv;
            qip[r] += lr * wij[tt].x;
            qjp[r] += lr * wij[tt].y;
        }
    }
    #pragma unroll
    for (int m = 1; m < 16; m <<= 1) {
        #pragma unroll
        for (int r = 0; r < 4; ++r) {
            qip[r] += __shfl_xor(qip[r], m);
            qjp[r] += __shfl_xor(qjp[r], m);
        }
    }
    if (tile < NT_ && rc == 0) {
        #pragma unroll
        for (int r = 0; r < 4; ++r) {
            int node = tile * 16 + kg * 4 + r;
            qi[b * N_ + node] = qip[r];
            qj[b * N_ + node] = qjp[r];
        }
    }
}

// gpart reduction (coalesced) + last-block qg/noop compute (fused)
__global__ __launch_bounds__(512) void k_greduce(
    const float* __restrict__ gpart, float* __restrict__ g,
    unsigned* __restrict__ cnt, const float* __restrict__ W6,
    const float* __restrict__ w5, const float* __restrict__ wno,
    float* __restrict__ qg, float* __restrict__ out)
{
    __shared__ float sp[4][B_][D_];
    __shared__ float sr[2][B_], srn[2][B_];
    __shared__ int lastf;

    const int t = threadIdx.x;          // 0..511
    {
        const int c0 = blockIdx.x * 25;
        float s = 0.f;
        #pragma unroll 5
        for (int i = 0; i < 25; ++i)
            s += gpart[(size_t)(c0 + i) * 512 + t];
        atomicAdd(&g[t], s);
    }
    __threadfence();
    __syncthreads();
    if (t == 0) {
        unsigned old = atomicAdd(cnt, 1u);
        lastf = (old == GRB_ - 1) ? 1 : 0;
    }
    __syncthreads();
    if (!lastf) return;
    __threadfence();   // acquire

    const int col = t & 127, q = t >> 7;
    {
        float p[B_] = {0, 0, 0, 0};
        for (int d = q * 32; d < q * 32 + 32; ++d) {
            float w6 = W6[d * D_ + col];
            #pragma unroll
            for (int b = 0; b < B_; ++b) p[b] += g[b * D_ + d] * w6;
        }
        #pragma unroll
        for (int b = 0; b < B_; ++b) sp[q][b][col] = p[b];
    }
    __syncthreads();
    if (t < 128) {
        float vq[B_], vn[B_];
        #pragma unroll
        for (int b = 0; b < B_; ++b) {
            float pp = sp[0][b][t] + sp[1][b][t] + sp[2][b][t] + sp[3][b][t];
            float lr = (pp >= 0.f) ? pp : 0.01f * pp;
            vq[b] = lr * w5[t];
            vn[b] = g[b * D_ + t] * wno[t];
        }
        #pragma unroll
        for (int m = 1; m < 64; m <<= 1) {
            #pragma unroll
            for (int b = 0; b < B_; ++b) {
                vq[b] += __shfl_xor(vq[b], m);
                vn[b] += __shfl_xor(vn[b], m);
            }
        }
        if ((t & 63) == 0) {
            #pragma unroll
            for (int b = 0; b < B_; ++b) { sr[t >> 6][b] = vq[b]; srn[t >> 6][b] = vn[b]; }
        }
    }
    __syncthreads();
    if (t == 0) {
        #pragma unroll
        for (int b = 0; b < B_; ++b) {
            qg[b] = sr[0][b] + sr[1][b];
            out[(size_t)b * (E_ + 1) + E_] = srn[0][b] + srn[1][b];
        }
    }
}

__global__ __launch_bounds__(256) void k_edge(
    const int* __restrict__ edges, const int* __restrict__ flag,
    const float* __restrict__ qg, const float* __restrict__ qi,
    const float* __restrict__ qj, float* __restrict__ out)
{
    int e = blockIdx.x * 256 + threadIdx.x;
    if (e >= E_) return;
    int u, v;
    if (*flag) { int4 w = ((const int4*)edges)[e]; u = w.x; v = w.z; }
    else       { int2 w = ((const int2*)edges)[e]; u = w.x; v = w.y; }
    float q0 = qg[0], q1 = qg[1], q2 = qg[2], q3 = qg[3];
    out[0 * (size_t)(E_ + 1) + e] = q0 + qi[0 * N_ + u] + qj[0 * N_ + v];
    out[1 * (size_t)(E_ + 1) + e] = q1 + qi[1 * N_ + u] + qj[1 * N_ + v];
    out[2 * (size_t)(E_ + 1) + e] = q2 + qi[2 * N_ + u] + qj[2 * N_ + v];
    out[3 * (size_t)(E_ + 1) + e] = q3 + qi[3 * N_ + u] + qj[3 * N_ + v];
}

extern "C" void kernel_launch(void* const* d_in, const int* in_sizes, int n_in,
                              void* d_out, int out_size, void* d_ws, size_t ws_size,
                              hipStream_t stream)
{
    const float* emb   = (const float*)d_in[0];
    const int*   edges = (const int*)d_in[1];
    const float* W6    = (const float*)d_in[2];
    const float* W7    = (const float*)d_in[3];
    const float* w5    = (const float*)d_in[4];
    const float* wno   = (const float*)d_in[5];
    float* out = (float*)d_out;

    float* W = (float*)d_ws;
    int*      flag  = (int*)W;
    unsigned* cnt   = (unsigned*)(W + 4);
    float*    qg    = W + 8;
    float*    g     = W + 128;
    float2*   w5f   = (float2*)(W + 640);
    bf16x8*   w7f   = (bf16x8*)(W + 1024);
    float*    gpart = W + 9216;
    float*    qi    = W + 649216;
    float*    qj    = W + 729216;

    hipLaunchKernelGGL(k_prep, dim3(9), dim3(256), 0, stream,
                       W7, w5, (const unsigned*)edges, flag, cnt, g, w5f, w7f);
    hipLaunchKernelGGL(k_main, dim3(313, B_), dim3(256), 0, stream,
                       emb, w7f, w5f, gpart, qi, qj);
    hipLaunchKernelGGL(k_greduce, dim3(GRB_), dim3(512), 0, stream,
                       gpart, g, cnt, W6, w5, wno, qg, out);
    hipLaunchKernelGGL(k_edge, dim3((E_ + 255) / 256), dim3(256), 0, stream,
                       edges, flag, qg, qi, qj, out);
}

// Round 12
// 44.372 us; speedup vs baseline: 1.1313x; 1.0866x over previous
//
#include <hip/hip_runtime.h>
#include <hip/hip_bf16.h>

#define B_ 4
#define N_ 20000
#define D_ 128
#define E_ 100000
#define NT_ 1250     // 16-node tiles (20000/16 exact)
#define GXM_ 79      // ceil(1250/16)
#define GRB_ 50      // greduce blocks

typedef __attribute__((ext_vector_type(8))) short bf16x8;
typedef __attribute__((ext_vector_type(4))) float f32x4;

// ws layout (float units):
// [0]              flag (int)
// [8,12)           qg (B_)
// [128,640)        g (B_ x D_)
// [640,896)        w5f (float2[128]: {w5_i[c], w5_j[c]})
// [1024,9216)      w7f: 2048 x bf16x8 (32 KB), MFMA B-fragment order
// [9216,649216)    gpart[1250][512]
// [649216,729216)  qi (B x N)
// [729216,809216)  qj (B x N)

__global__ __launch_bounds__(256) void k_prep(
    const float* __restrict__ W7, const float* __restrict__ w5,
    const unsigned* __restrict__ ew, int* __restrict__ flag,
    float* __restrict__ g, float2* __restrict__ w5f, bf16x8* __restrict__ w7f)
{
    const int bx = blockIdx.x, t = threadIdx.x;
    if (bx == 8) {
        g[t] = 0.f; g[t + 256] = 0.f;
        if (t < 128) w5f[t] = make_float2(w5[D_ + t], w5[2 * D_ + t]);
        if (t < 64) {
            unsigned v = ew[2 * t + 1];      // high words if int64 (all zero)
            unsigned long long any = __ballot(v != 0u);
            if (t == 0) *flag = (any == 0ULL) ? 1 : 0;
        }
        return;
    }
    int f = bx * 256 + t;                    // 0..2047
    int tt = f >> 8, s = (f >> 6) & 3, lane = f & 63;
    int kg = lane >> 4, rc = lane & 15;
    int col = tt * 16 + rc, k0 = s * 32 + kg * 8;
    union { bf16x8 v; __hip_bfloat16 h[8]; } pk;
    #pragma unroll
    for (int m = 0; m < 8; ++m)
        pk.h[m] = __float2bfloat16(W7[(k0 + m) * D_ + col]);
    w7f[f] = pk.v;
}

// Mega-block k_main: 1024 threads = 16 waves, one tile per wave.
// Forces 16+ waves/CU residency; per-wave code identical to the R5 champion.
__global__ __launch_bounds__(1024) void k_main(
    const float* __restrict__ emb, const bf16x8* __restrict__ w7f,
    const float2* __restrict__ w5f, float* __restrict__ gpart,
    float* __restrict__ qi, float* __restrict__ qj)
{
    __shared__ bf16x8 sB[2048];   // fragment order: idx = tt*256 + s*64 + lane

    const int t = threadIdx.x, b = blockIdx.y;
    const int wv = t >> 6, lane = t & 63, rc = lane & 15, kg = lane >> 4;
    const int tile = blockIdx.x * 16 + wv;
    const int tc = (tile < NT_) ? tile : (NT_ - 1);

    // ---- issue A loads (HBM/L3, deepest latency) first
    const float4* p = (const float4*)(emb + (size_t)b * N_ * D_)
                      + ((size_t)(tc * 16 + rc)) * 32 + kg * 2;
    float4 a[8];
    #pragma unroll
    for (int s = 0; s < 4; ++s) { a[2*s] = p[s*8]; a[2*s+1] = p[s*8+1]; }

    // ---- stage B (coalesced uint4, L2-resident source; 2 per thread)
    {
        const uint4* src = (const uint4*)w7f;
        uint4* dst = (uint4*)sB;
        dst[t]        = src[t];
        dst[t + 1024] = src[t + 1024];
    }
    float2 wij[8];
    #pragma unroll
    for (int tt = 0; tt < 8; ++tt) wij[tt] = w5f[tt * 16 + rc];
    __syncthreads();

    // ---- cvt A to bf16 fragments (a[] stays live for g)
    bf16x8 pk[4];
    #pragma unroll
    for (int s = 0; s < 4; ++s) {
        union { bf16x8 v; __hip_bfloat16 h[8]; } u;
        float4 x = a[2*s], y = a[2*s+1];
        u.h[0] = __float2bfloat16(x.x); u.h[1] = __float2bfloat16(x.y);
        u.h[2] = __float2bfloat16(x.z); u.h[3] = __float2bfloat16(x.w);
        u.h[4] = __float2bfloat16(y.x); u.h[5] = __float2bfloat16(y.y);
        u.h[6] = __float2bfloat16(y.z); u.h[7] = __float2bfloat16(y.w);
        pk[s] = u.v;
    }

    // ---- g partials (frees a[]; stores fly under MFMA)
    #pragma unroll
    for (int m = 1; m < 16; m <<= 1) {
        #pragma unroll
        for (int i = 0; i < 8; ++i) {
            a[i].x += __shfl_xor(a[i].x, m);
            a[i].y += __shfl_xor(a[i].y, m);
            a[i].z += __shfl_xor(a[i].z, m);
            a[i].w += __shfl_xor(a[i].w, m);
        }
    }
    if (tile < NT_ && rc == 0) {
        float* gp = gpart + (size_t)tile * 512 + b * 128;
        #pragma unroll
        for (int s = 0; s < 4; ++s) {
            int c0 = s * 32 + kg * 8;
            *reinterpret_cast<float4*>(gp + c0)     = a[2*s];
            *reinterpret_cast<float4*>(gp + c0 + 4) = a[2*s+1];
        }
    }

    // ---- MFMA: 16 nodes x 128 cols, K=128
    f32x4 acc[8] = {};
    #pragma unroll
    for (int s = 0; s < 4; ++s)
        #pragma unroll
        for (int tt = 0; tt < 8; ++tt)
            acc[tt] = __builtin_amdgcn_mfma_f32_16x16x32_bf16(pk[s], sB[tt * 256 + s * 64 + lane], acc[tt], 0, 0, 0);

    // ---- epilogue: leaky, dot w5_i/w5_j, shfl-reduce over rc, store
    float qip[4] = {0,0,0,0}, qjp[4] = {0,0,0,0};
    #pragma unroll
    for (int tt = 0; tt < 8; ++tt) {
        #pragma unroll
        for (int r = 0; r < 4; ++r) {
            float pv = acc[tt][r];
            float lr = (pv >= 0.f) ? pv : 0.01f * pv;
            qip[r] += lr * wij[tt].x;
            qjp[r] += lr * wij[tt].y;
        }
    }
    #pragma unroll
    for (int m = 1; m < 16; m <<= 1) {
        #pragma unroll
        for (int r = 0; r < 4; ++r) {
            qip[r] += __shfl_xor(qip[r], m);
            qjp[r] += __shfl_xor(qjp[r], m);
        }
    }
    if (tile < NT_ && rc == 0) {
        #pragma unroll
        for (int r = 0; r < 4; ++r) {
            int node = tile * 16 + kg * 4 + r;
            qi[b * N_ + node] = qip[r];
            qj[b * N_ + node] = qjp[r];
        }
    }
}

// parallel reduction of gpart: 50 blocks x 512 threads, 25 tiles each, coalesced
__global__ __launch_bounds__(512) void k_greduce(
    const float* __restrict__ gpart, float* __restrict__ g)
{
    const int t = threadIdx.x;          // column 0..511
    const int c0 = blockIdx.x * 25;     // tile chunk
    float s = 0.f;
    #pragma unroll 5
    for (int i = 0; i < 25; ++i)
        s += gpart[(size_t)(c0 + i) * 512 + t];
    atomicAdd(&g[t], s);
}

__global__ __launch_bounds__(256) void k_qg(
    const float* __restrict__ g, const float* __restrict__ W6,
    const float* __restrict__ w5, const float* __restrict__ wno,
    float* __restrict__ qg, float* __restrict__ out)
{
    __shared__ float sg[128];
    __shared__ float sp2[2][128];
    __shared__ float sr[2], srn[2];
    const int b = blockIdx.x, t = threadIdx.x;
    const int col = t & 127, h = t >> 7;

    if (t < 128) sg[t] = g[b * D_ + t];
    __syncthreads();

    float pv = 0.f;
    #pragma unroll 8
    for (int d = h * 64; d < h * 64 + 64; ++d)
        pv += sg[d] * W6[d * D_ + col];
    sp2[h][col] = pv;
    __syncthreads();

    if (t < 128) {
        float pp = sp2[0][t] + sp2[1][t];
        float lr = (pp >= 0.f) ? pp : 0.01f * pp;
        float vq = lr * w5[t];       // w5_g
        float vn = sg[t] * wno[t];   // noop
        #pragma unroll
        for (int m = 1; m < 64; m <<= 1) {
            vq += __shfl_xor(vq, m);
            vn += __shfl_xor(vn, m);
        }
        if ((t & 63) == 0) { sr[t >> 6] = vq; srn[t >> 6] = vn; }
    }
    __syncthreads();
    if (t == 0) {
        qg[b] = sr[0] + sr[1];
        out[(size_t)b * (E_ + 1) + E_] = srn[0] + srn[1];
    }
}

__global__ __launch_bounds__(256) void k_edge(
    const int* __restrict__ edges, const int* __restrict__ flag,
    const float* __restrict__ qg, const float* __restrict__ qi,
    const float* __restrict__ qj, float* __restrict__ out)
{
    int e = blockIdx.x * 256 + threadIdx.x;
    if (e >= E_) return;
    int u, v;
    if (*flag) { int4 w = ((const int4*)edges)[e]; u = w.x; v = w.z; }
    else       { int2 w = ((const int2*)edges)[e]; u = w.x; v = w.y; }
    float q0 = qg[0], q1 = qg[1], q2 = qg[2], q3 = qg[3];
    out[0 * (size_t)(E_ + 1) + e] = q0 + qi[0 * N_ + u] + qj[0 * N_ + v];
    out[1 * (size_t)(E_ + 1) + e] = q1 + qi[1 * N_ + u] + qj[1 * N_ + v];
    out[2 * (size_t)(E_ + 1) + e] = q2 + qi[2 * N_ + u] + qj[2 * N_ + v];
    out[3 * (size_t)(E_ + 1) + e] = q3 + qi[3 * N_ + u] + qj[3 * N_ + v];
}

extern "C" void kernel_launch(void* const* d_in, const int* in_sizes, int n_in,
                              void* d_out, int out_size, void* d_ws, size_t ws_size,
                              hipStream_t stream)
{
    const float* emb   = (const float*)d_in[0];
    const int*   edges = (const int*)d_in[1];
    const float* W6    = (const float*)d_in[2];
    const float* W7    = (const float*)d_in[3];
    const float* w5    = (const float*)d_in[4];
    const float* wno   = (const float*)d_in[5];
    float* out = (float*)d_out;

    float* W = (float*)d_ws;
    int*     flag  = (int*)W;
    float*   qg    = W + 8;
    float*   g     = W + 128;
    float2*  w5f   = (float2*)(W + 640);
    bf16x8*  w7f   = (bf16x8*)(W + 1024);
    float*   gpart = W + 9216;
    float*   qi    = W + 649216;
    float*   qj    = W + 729216;

    hipLaunchKernelGGL(k_prep, dim3(9), dim3(256), 0, stream,
                       W7, w5, (const unsigned*)edges, flag, g, w5f, w7f);
    hipLaunchKernelGGL(k_main, dim3(GXM_, B_), dim3(1024), 0, stream,
                       emb, w7f, w5f, gpart, qi, qj);
    hipLaunchKernelGGL(k_greduce, dim3(GRB_), dim3(512), 0, stream, gpart, g);
    hipLaunchKernelGGL(k_qg, dim3(B_), dim3(256), 0, stream,
                       g, W6, w5, wno, qg, out);
    hipLaunchKernelGGL(k_edge, dim3((E_ + 255) / 256), dim3(256), 0, stream,
                       edges, flag, qg, qi, qj, out);
}